// Round 1
// baseline (1176.250 us; speedup 1.0000x reference)
//
#include <hip/hip_runtime.h>

// GCN: h1 = relu(GCNConv(x,W1,b1)); h2 = GCNConv(h1,W2,b2); out = meanpool(h2)@Wfc+bfc
// Trick: s[i] = (h@W)[i]*dinv[i]; conv_out[i] = dinv[i]*(sum_{e:dst=i} s[src[e]] + s[i]) + b
// (AGG initialized to s via D2D copy -> self-loop term free, no per-edge norm multiply.)

constexpr int H = 32;

__global__ void deg_kernel(const int* __restrict__ dst, float* __restrict__ deg, int E) {
    int e = blockIdx.x * blockDim.x + threadIdx.x;
    if (e < E) atomicAdd(&deg[dst[e]], 1.0f);
}

__global__ void dinv_kernel(float* __restrict__ deg, int N) {
    int i = blockIdx.x * blockDim.x + threadIdx.x;
    if (i < N) deg[i] = rsqrtf(deg[i] + 1.0f);   // deg incl. self-loop
}

// s1[i][j] = dinv[i] * sum_k x[i][k] * W1[k][j]   (one thread per node)
__global__ void lin1_kernel(const float* __restrict__ x, const float* __restrict__ W1,
                            const float* __restrict__ dinv, float* __restrict__ S, int N) {
    int i = blockIdx.x * blockDim.x + threadIdx.x;
    if (i >= N) return;
    float xv[5];
#pragma unroll
    for (int k = 0; k < 5; k++) xv[k] = x[i * 5 + k];
    float di = dinv[i];
#pragma unroll
    for (int j = 0; j < H; j++) {
        float acc = 0.f;
#pragma unroll
        for (int k = 0; k < 5; k++) acc = fmaf(xv[k], W1[k * H + j], acc);
        S[i * H + j] = acc * di;
    }
}

// In-place: S holds h1 (N x 32); replace row i with dinv[i] * (h1[i] @ W2).
// Safe: each thread owns one full row, loads it to regs before writing.
__global__ void lin2_kernel(const float* __restrict__ W2, const float* __restrict__ dinv,
                            float* __restrict__ S, int N) {
    __shared__ float w[H * H];
    for (int t = threadIdx.x; t < H * H; t += blockDim.x) w[t] = W2[t];
    __syncthreads();
    int i = blockIdx.x * blockDim.x + threadIdx.x;
    if (i >= N) return;
    float h[H];
#pragma unroll
    for (int k = 0; k < H; k++) h[k] = S[i * H + k];
    float di = dinv[i];
#pragma unroll
    for (int j = 0; j < H; j++) {
        float acc = 0.f;
#pragma unroll
        for (int k = 0; k < H; k++) acc = fmaf(h[k], w[k * H + j], acc);
        S[i * H + j] = acc * di;
    }
}

// thread t -> edge e = t>>5, column j = t&31. 32 lanes cover one 128B line of AGG[dst].
__global__ void edge_agg_kernel(const int* __restrict__ src, const int* __restrict__ dst,
                                const float* __restrict__ S, float* __restrict__ AGG, int E) {
    int t = blockIdx.x * blockDim.x + threadIdx.x;
    int e = t >> 5, j = t & 31;
    if (e >= E) return;
    int u = src[e], v = dst[e];
    atomicAdd(&AGG[(size_t)v * H + j], S[(size_t)u * H + j]);
}

// h1 = relu(dinv*AGG + b1), written back into S
__global__ void post1_kernel(const float* __restrict__ AGG, const float* __restrict__ b1,
                             const float* __restrict__ dinv, float* __restrict__ S, int N) {
    int t = blockIdx.x * blockDim.x + threadIdx.x;
    if (t >= N * H) return;
    int i = t >> 5, j = t & 31;
    float v = fmaf(dinv[i], AGG[t], b1[j]);
    S[t] = fmaxf(v, 0.f);
}

// h2 = dinv*AGG + b2, atomically accumulated into pooled[batch[i]]
__global__ void post2_pool_kernel(const float* __restrict__ AGG, const float* __restrict__ b2,
                                  const float* __restrict__ dinv, const int* __restrict__ batch,
                                  float* __restrict__ pooled, int N) {
    int t = blockIdx.x * blockDim.x + threadIdx.x;
    if (t >= N * H) return;
    int i = t >> 5, j = t & 31;
    float v = fmaf(dinv[i], AGG[t], b2[j]);
    atomicAdd(&pooled[(size_t)batch[i] * H + j], v);
}

// batch is sorted: graph boundaries -> counts without atomics
__global__ void bounds_kernel(const int* __restrict__ batch, int* __restrict__ startg,
                              int* __restrict__ endg, int N) {
    int i = blockIdx.x * blockDim.x + threadIdx.x;
    if (i >= N) return;
    int g = batch[i];
    if (i == 0 || batch[i - 1] != g) startg[g] = i;
    if (i == N - 1 || batch[i + 1] != g) endg[g] = i + 1;
}

__global__ void final_kernel(const float* __restrict__ pooled, const int* __restrict__ startg,
                             const int* __restrict__ endg, const float* __restrict__ Wfc,
                             const float* __restrict__ bfc, float* __restrict__ out, int G) {
    int g = blockIdx.x * blockDim.x + threadIdx.x;
    if (g >= G) return;
    float cnt = (float)(endg[g] - startg[g]);
    float inv = 1.0f / fmaxf(cnt, 1.0f);
    float s0 = 0.f, s1 = 0.f;
#pragma unroll
    for (int j = 0; j < H; j++) {
        float p = pooled[g * H + j] * inv;
        s0 = fmaf(p, Wfc[j * 2 + 0], s0);
        s1 = fmaf(p, Wfc[j * 2 + 1], s1);
    }
    out[g * 2 + 0] = s0 + bfc[0];
    out[g * 2 + 1] = s1 + bfc[1];
}

extern "C" void kernel_launch(void* const* d_in, const int* in_sizes, int n_in,
                              void* d_out, int out_size, void* d_ws, size_t ws_size,
                              hipStream_t stream) {
    const float* x    = (const float*)d_in[0];
    const float* W1   = (const float*)d_in[1];
    const float* b1   = (const float*)d_in[2];
    const float* W2   = (const float*)d_in[3];
    const float* b2   = (const float*)d_in[4];
    const float* Wfc  = (const float*)d_in[5];
    const float* bfc  = (const float*)d_in[6];
    const int*   eidx = (const int*)d_in[7];
    const int*   batch= (const int*)d_in[8];
    float* out = (float*)d_out;

    const int N = in_sizes[0] / 5;
    const int E = in_sizes[7] / 2;
    const int G = out_size / 2;

    const int* src = eidx;
    const int* dst = eidx + E;

    // workspace layout (bytes, 256-aligned)
    char* ws = (char*)d_ws;
    size_t off = 0;
    auto alloc = [&](size_t bytes) { char* p = ws + off; off = (off + bytes + 255) & ~(size_t)255; return p; };
    float* dinv   = (float*)alloc((size_t)N * 4);
    float* S      = (float*)alloc((size_t)N * H * 4);
    float* AGG    = (float*)alloc((size_t)N * H * 4);
    float* pooled = (float*)alloc((size_t)G * H * 4);
    int*   startg = (int*)alloc((size_t)G * 4);
    int*   endg   = (int*)alloc((size_t)G * 4);
    (void)ws_size;

    const int T = 256;
    auto nb = [&](long long n) { return (int)((n + T - 1) / T); };

    // zero: deg, pooled+startg+endg (contiguous-ish; pooled..endg zeroed separately)
    hipMemsetAsync(dinv, 0, (size_t)N * 4, stream);
    hipMemsetAsync(pooled, 0, (size_t)G * H * 4, stream);
    hipMemsetAsync(startg, 0, (size_t)G * 4, stream);
    hipMemsetAsync(endg, 0, (size_t)G * 4, stream);

    deg_kernel<<<nb(E), T, 0, stream>>>(dst, dinv, E);
    dinv_kernel<<<nb(N), T, 0, stream>>>(dinv, N);

    // ---- layer 1 ----
    lin1_kernel<<<nb(N), T, 0, stream>>>(x, W1, dinv, S, N);
    hipMemcpyAsync(AGG, S, (size_t)N * H * 4, hipMemcpyDeviceToDevice, stream); // self-loop init
    edge_agg_kernel<<<nb((long long)E * H), T, 0, stream>>>(src, dst, S, AGG, E);
    post1_kernel<<<nb((long long)N * H), T, 0, stream>>>(AGG, b1, dinv, S, N);

    // ---- layer 2 ----
    lin2_kernel<<<nb(N), T, 0, stream>>>(W2, dinv, S, N);
    hipMemcpyAsync(AGG, S, (size_t)N * H * 4, hipMemcpyDeviceToDevice, stream);
    edge_agg_kernel<<<nb((long long)E * H), T, 0, stream>>>(src, dst, S, AGG, E);

    // ---- pool + fc ----
    bounds_kernel<<<nb(N), T, 0, stream>>>(batch, startg, endg, N);
    post2_pool_kernel<<<nb((long long)N * H), T, 0, stream>>>(AGG, b2, dinv, batch, pooled, N);
    final_kernel<<<nb(G), T, 0, stream>>>(pooled, startg, endg, Wfc, bfc, out, G);
}

// Round 2
// 826.381 us; speedup vs baseline: 1.4234x; 1.4234x over previous
//
#include <hip/hip_runtime.h>

// GCN: h1 = relu(GCNConv(x,W1,b1)); h2 = GCNConv(h1,W2,b2); out = meanpool(h2)@Wfc+bfc
// Trick: s[i] = (h@W)[i]*dinv[i]; conv_out[i] = dinv[i]*(sum_{e:dst=i} s[src[e]] + s[i]) + b
// (AGG initialized to s via D2D copy -> self-loop term free, no per-edge norm multiply.)
// Pooling: batch is SORTED -> segmented reduction with register accumulation,
// one atomic per (graph-run x thread) instead of one per (node x column).

constexpr int H = 32;
constexpr int POOL_CHUNK = 1024;   // nodes per block in pool_kernel

__global__ void deg_kernel(const int* __restrict__ dst, float* __restrict__ deg, int E) {
    int e = blockIdx.x * blockDim.x + threadIdx.x;
    if (e < E) atomicAdd(&deg[dst[e]], 1.0f);
}

__global__ void dinv_kernel(float* __restrict__ deg, int N) {
    int i = blockIdx.x * blockDim.x + threadIdx.x;
    if (i < N) deg[i] = rsqrtf(deg[i] + 1.0f);   // deg incl. self-loop
}

// s1[i][j] = dinv[i] * sum_k x[i][k] * W1[k][j]   (one thread per node)
__global__ void lin1_kernel(const float* __restrict__ x, const float* __restrict__ W1,
                            const float* __restrict__ dinv, float* __restrict__ S, int N) {
    int i = blockIdx.x * blockDim.x + threadIdx.x;
    if (i >= N) return;
    float xv[5];
#pragma unroll
    for (int k = 0; k < 5; k++) xv[k] = x[i * 5 + k];
    float di = dinv[i];
#pragma unroll
    for (int j = 0; j < H; j++) {
        float acc = 0.f;
#pragma unroll
        for (int k = 0; k < 5; k++) acc = fmaf(xv[k], W1[k * H + j], acc);
        S[i * H + j] = acc * di;
    }
}

// In-place: S holds h1 (N x 32); replace row i with dinv[i] * (h1[i] @ W2).
__global__ void lin2_kernel(const float* __restrict__ W2, const float* __restrict__ dinv,
                            float* __restrict__ S, int N) {
    __shared__ float w[H * H];
    for (int t = threadIdx.x; t < H * H; t += blockDim.x) w[t] = W2[t];
    __syncthreads();
    int i = blockIdx.x * blockDim.x + threadIdx.x;
    if (i >= N) return;
    float h[H];
#pragma unroll
    for (int k = 0; k < H; k++) h[k] = S[i * H + k];
    float di = dinv[i];
#pragma unroll
    for (int j = 0; j < H; j++) {
        float acc = 0.f;
#pragma unroll
        for (int k = 0; k < H; k++) acc = fmaf(h[k], w[k * H + j], acc);
        S[i * H + j] = acc * di;
    }
}

// thread t -> edge e = t>>5, column j = t&31. 32 lanes cover one 128B line of AGG[dst].
__global__ void edge_agg_kernel(const int* __restrict__ src, const int* __restrict__ dst,
                                const float* __restrict__ S, float* __restrict__ AGG, int E) {
    int t = blockIdx.x * blockDim.x + threadIdx.x;
    int e = t >> 5, j = t & 31;
    if (e >= E) return;
    int u = src[e], v = dst[e];
    atomicAdd(&AGG[(size_t)v * H + j], S[(size_t)u * H + j]);
}

// h1 = relu(dinv*AGG + b1), written back into S
__global__ void post1_kernel(const float* __restrict__ AGG, const float* __restrict__ b1,
                             const float* __restrict__ dinv, float* __restrict__ S, int N) {
    int t = blockIdx.x * blockDim.x + threadIdx.x;
    if (t >= N * H) return;
    int i = t >> 5, j = t & 31;
    float v = fmaf(dinv[i], AGG[t], b1[j]);
    S[t] = fmaxf(v, 0.f);
}

// Segmented mean-pool numerator: pooled[g][j] += sum_{i in g} dinv[i]*AGG[i][j].
// batch sorted -> register-accumulate runs, atomic only at run boundaries.
__global__ void pool_kernel(const float* __restrict__ AGG, const float* __restrict__ dinv,
                            const int* __restrict__ batch, float* __restrict__ pooled, int N) {
    const int j = threadIdx.x & 31;
    const int r = threadIdx.x >> 5;        // 0..7
    const int ROWS = 256 / 32;             // 8 rows in flight per block
    long long base = (long long)blockIdx.x * POOL_CHUNK;
    long long end  = base + POOL_CHUNK;
    if (end > N) end = N;
    float acc = 0.f;
    int cur_g = -1;
    for (long long i = base + r; i < end; i += ROWS) {
        int g = batch[i];
        float v = dinv[i] * AGG[i * H + j];
        if (g != cur_g) {
            if (cur_g >= 0) atomicAdd(&pooled[(size_t)cur_g * H + j], acc);
            acc = 0.f;
            cur_g = g;
        }
        acc += v;
    }
    if (cur_g >= 0) atomicAdd(&pooled[(size_t)cur_g * H + j], acc);
}

// batch is sorted: graph boundaries -> counts without atomics
__global__ void bounds_kernel(const int* __restrict__ batch, int* __restrict__ startg,
                              int* __restrict__ endg, int N) {
    int i = blockIdx.x * blockDim.x + threadIdx.x;
    if (i >= N) return;
    int g = batch[i];
    if (i == 0 || batch[i - 1] != g) startg[g] = i;
    if (i == N - 1 || batch[i + 1] != g) endg[g] = i + 1;
}

// out[g] = (pooled[g]/cnt + b2) @ Wfc + bfc   (b2 folded in here: mean(h+b2)=mean(h)+b2)
__global__ void final_kernel(const float* __restrict__ pooled, const int* __restrict__ startg,
                             const int* __restrict__ endg, const float* __restrict__ b2,
                             const float* __restrict__ Wfc, const float* __restrict__ bfc,
                             float* __restrict__ out, int G) {
    int g = blockIdx.x * blockDim.x + threadIdx.x;
    if (g >= G) return;
    float cnt = (float)(endg[g] - startg[g]);
    float inv = 1.0f / fmaxf(cnt, 1.0f);
    float s0 = 0.f, s1 = 0.f;
#pragma unroll
    for (int j = 0; j < H; j++) {
        float p = fmaf(pooled[g * H + j], inv, b2[j]);
        s0 = fmaf(p, Wfc[j * 2 + 0], s0);
        s1 = fmaf(p, Wfc[j * 2 + 1], s1);
    }
    out[g * 2 + 0] = s0 + bfc[0];
    out[g * 2 + 1] = s1 + bfc[1];
}

extern "C" void kernel_launch(void* const* d_in, const int* in_sizes, int n_in,
                              void* d_out, int out_size, void* d_ws, size_t ws_size,
                              hipStream_t stream) {
    const float* x    = (const float*)d_in[0];
    const float* W1   = (const float*)d_in[1];
    const float* b1   = (const float*)d_in[2];
    const float* W2   = (const float*)d_in[3];
    const float* b2   = (const float*)d_in[4];
    const float* Wfc  = (const float*)d_in[5];
    const float* bfc  = (const float*)d_in[6];
    const int*   eidx = (const int*)d_in[7];
    const int*   batch= (const int*)d_in[8];
    float* out = (float*)d_out;

    const int N = in_sizes[0] / 5;
    const int E = in_sizes[7] / 2;
    const int G = out_size / 2;

    const int* src = eidx;
    const int* dst = eidx + E;

    // workspace layout (bytes, 256-aligned)
    char* ws = (char*)d_ws;
    size_t off = 0;
    auto alloc = [&](size_t bytes) { char* p = ws + off; off = (off + bytes + 255) & ~(size_t)255; return p; };
    float* dinv   = (float*)alloc((size_t)N * 4);
    float* S      = (float*)alloc((size_t)N * H * 4);
    float* AGG    = (float*)alloc((size_t)N * H * 4);
    float* pooled = (float*)alloc((size_t)G * H * 4);
    int*   startg = (int*)alloc((size_t)G * 4);
    int*   endg   = (int*)alloc((size_t)G * 4);
    (void)ws_size;

    const int T = 256;
    auto nb = [&](long long n) { return (int)((n + T - 1) / T); };

    hipMemsetAsync(dinv, 0, (size_t)N * 4, stream);
    hipMemsetAsync(pooled, 0, (size_t)G * H * 4, stream);
    hipMemsetAsync(startg, 0, (size_t)G * 4, stream);
    hipMemsetAsync(endg, 0, (size_t)G * 4, stream);

    deg_kernel<<<nb(E), T, 0, stream>>>(dst, dinv, E);
    dinv_kernel<<<nb(N), T, 0, stream>>>(dinv, N);

    // ---- layer 1 ----
    lin1_kernel<<<nb(N), T, 0, stream>>>(x, W1, dinv, S, N);
    hipMemcpyAsync(AGG, S, (size_t)N * H * 4, hipMemcpyDeviceToDevice, stream); // self-loop init
    edge_agg_kernel<<<nb((long long)E * H), T, 0, stream>>>(src, dst, S, AGG, E);
    post1_kernel<<<nb((long long)N * H), T, 0, stream>>>(AGG, b1, dinv, S, N);

    // ---- layer 2 ----
    lin2_kernel<<<nb(N), T, 0, stream>>>(W2, dinv, S, N);
    hipMemcpyAsync(AGG, S, (size_t)N * H * 4, hipMemcpyDeviceToDevice, stream);
    edge_agg_kernel<<<nb((long long)E * H), T, 0, stream>>>(src, dst, S, AGG, E);

    // ---- pool + fc ----
    bounds_kernel<<<nb(N), T, 0, stream>>>(batch, startg, endg, N);
    pool_kernel<<<(N + POOL_CHUNK - 1) / POOL_CHUNK, T, 0, stream>>>(AGG, dinv, batch, pooled, N);
    final_kernel<<<nb(G), T, 0, stream>>>(pooled, startg, endg, b2, Wfc, bfc, out, G);
}

// Round 3
// 683.030 us; speedup vs baseline: 1.7221x; 1.2099x over previous
//
#include <hip/hip_runtime.h>

// GCN via CSR pull-aggregation (no scatter atomics on the feature matrix).
// s[i] = (h@W)[i]*dinv[i];  conv[i] = dinv[i]*(s[i] + sum_{u in nbr_in(i)} s[u]) + b
// CSR built per call: histogram(dst) -> exclusive scan -> scatter src by dst.
// deg comes free from the histogram; self-loop is a register init in the pull.

constexpr int H = 32;
constexpr int POOL_CHUNK = 1024;

// ---- CSR build ----
__global__ void hist_kernel(const int* __restrict__ dst, int* __restrict__ cnt, int E) {
    int e = blockIdx.x * blockDim.x + threadIdx.x;
    if (e < E) atomicAdd(&cnt[dst[e]], 1);
}

// scan1: in-place exclusive scan of 1024-element chunks of R; block totals -> bsum
__global__ void scan1_kernel(int* __restrict__ R, int* __restrict__ bsum, int N) {
    __shared__ int sh[256];
    int base = blockIdx.x * 1024 + threadIdx.x * 4;
    int v[4]; int s = 0;
#pragma unroll
    for (int q = 0; q < 4; q++) { int idx = base + q; v[q] = (idx < N) ? R[idx] : 0; s += v[q]; }
    sh[threadIdx.x] = s;
    __syncthreads();
    for (int off = 1; off < 256; off <<= 1) {
        int t = (threadIdx.x >= off) ? sh[threadIdx.x - off] : 0;
        __syncthreads();
        sh[threadIdx.x] += t;
        __syncthreads();
    }
    int excl = sh[threadIdx.x] - s;
#pragma unroll
    for (int q = 0; q < 4; q++) { int idx = base + q; if (idx < N) R[idx] = excl; excl += v[q]; }
    if (threadIdx.x == 255) bsum[blockIdx.x] = sh[255];
}

// scan2: single block (1024 threads) exclusive scan of bsum[0..nb), nb <= 1024
__global__ void scan2_kernel(int* __restrict__ bsum, int nb) {
    __shared__ int sh[1024];
    int t = threadIdx.x;
    int orig = (t < nb) ? bsum[t] : 0;
    sh[t] = orig;
    __syncthreads();
    for (int off = 1; off < 1024; off <<= 1) {
        int v = (t >= off) ? sh[t - off] : 0;
        __syncthreads();
        sh[t] += v;
        __syncthreads();
    }
    if (t < nb) bsum[t] = sh[t] - orig;
}

__global__ void scan3_kernel(int* __restrict__ R, const int* __restrict__ bsum, int N) {
    int i = blockIdx.x * blockDim.x + threadIdx.x;
    if (i < N) R[i] += bsum[i >> 10];
}

// dinv[i] = rsqrt(deg_i + 1), deg from rowptr differences
__global__ void dinv_kernel(const int* __restrict__ R, float* __restrict__ dinv, int N, int E) {
    int i = blockIdx.x * blockDim.x + threadIdx.x;
    if (i >= N) return;
    int s = R[i];
    int e2 = (i == N - 1) ? E : R[i + 1];
    dinv[i] = rsqrtf((float)(e2 - s) + 1.0f);
}

__global__ void scatter_kernel(const int* __restrict__ src, const int* __restrict__ dst,
                               const int* __restrict__ R, int* __restrict__ cursor,
                               int* __restrict__ adj, int E) {
    int e = blockIdx.x * blockDim.x + threadIdx.x;
    if (e >= E) return;
    int v = dst[e];
    int pos = R[v] + atomicAdd(&cursor[v], 1);
    adj[pos] = src[e];
}

// ---- feature transforms ----
__global__ void lin1_kernel(const float* __restrict__ x, const float* __restrict__ W1,
                            const float* __restrict__ dinv, float* __restrict__ S, int N) {
    int i = blockIdx.x * blockDim.x + threadIdx.x;
    if (i >= N) return;
    float xv[5];
#pragma unroll
    for (int k = 0; k < 5; k++) xv[k] = x[i * 5 + k];
    float di = dinv[i];
#pragma unroll
    for (int j = 0; j < H; j++) {
        float acc = 0.f;
#pragma unroll
        for (int k = 0; k < 5; k++) acc = fmaf(xv[k], W1[k * H + j], acc);
        S[i * H + j] = acc * di;
    }
}

// In-place per-row transform: S[i] <- dinv[i] * (S[i] @ W2)
__global__ void lin2_kernel(const float* __restrict__ W2, const float* __restrict__ dinv,
                            float* __restrict__ S, int N) {
    __shared__ float w[H * H];
    for (int t = threadIdx.x; t < H * H; t += blockDim.x) w[t] = W2[t];
    __syncthreads();
    int i = blockIdx.x * blockDim.x + threadIdx.x;
    if (i >= N) return;
    float h[H];
#pragma unroll
    for (int k = 0; k < H; k++) h[k] = S[i * H + k];
    float di = dinv[i];
#pragma unroll
    for (int j = 0; j < H; j++) {
        float acc = 0.f;
#pragma unroll
        for (int k = 0; k < H; k++) acc = fmaf(h[k], w[k * H + j], acc);
        S[i * H + j] = acc * di;
    }
}

// ---- pull aggregation: out[i][j] = post( dinv[i]*(Sin[i][j] + sum_nbr Sin[u][j]) + bias[j] )
__global__ void pull_kernel(const float* __restrict__ Sin, const int* __restrict__ R,
                            const int* __restrict__ adj, const float* __restrict__ dinv,
                            const float* __restrict__ bias, float* __restrict__ Sout,
                            int N, int E, int relu) {
    int t = blockIdx.x * blockDim.x + threadIdx.x;
    int i = t >> 5, j = t & 31;
    if (i >= N) return;
    float acc = Sin[(size_t)i * H + j];                 // self-loop
    int s = R[i];
    int e2 = (i == N - 1) ? E : R[i + 1];
    for (int k = s; k < e2; k++) {
        int u = adj[k];
        acc += Sin[(size_t)u * H + j];
    }
    float val = fmaf(dinv[i], acc, bias ? bias[j] : 0.f);
    if (relu) val = fmaxf(val, 0.f);
    Sout[(size_t)i * H + j] = val;
}

// ---- pooling ----
__global__ void bounds_kernel(const int* __restrict__ batch, int* __restrict__ startg,
                              int* __restrict__ endg, int N) {
    int i = blockIdx.x * blockDim.x + threadIdx.x;
    if (i >= N) return;
    int g = batch[i];
    if (i == 0 || batch[i - 1] != g) startg[g] = i;
    if (i == N - 1 || batch[i + 1] != g) endg[g] = i + 1;
}

// segmented sum over sorted batch; one atomic per (run x thread)
__global__ void pool_kernel(const float* __restrict__ H2, const int* __restrict__ batch,
                            float* __restrict__ pooled, int N) {
    const int j = threadIdx.x & 31;
    const int r = threadIdx.x >> 5;
    const int ROWS = 256 / 32;
    long long base = (long long)blockIdx.x * POOL_CHUNK;
    long long end = base + POOL_CHUNK;
    if (end > N) end = N;
    float acc = 0.f;
    int cur_g = -1;
    for (long long i = base + r; i < end; i += ROWS) {
        int g = batch[i];
        float v = H2[i * H + j];
        if (g != cur_g) {
            if (cur_g >= 0) atomicAdd(&pooled[(size_t)cur_g * H + j], acc);
            acc = 0.f;
            cur_g = g;
        }
        acc += v;
    }
    if (cur_g >= 0) atomicAdd(&pooled[(size_t)cur_g * H + j], acc);
}

// out[g] = (pooled[g]/cnt + b2) @ Wfc + bfc   (b2 commutes through mean)
__global__ void final_kernel(const float* __restrict__ pooled, const int* __restrict__ startg,
                             const int* __restrict__ endg, const float* __restrict__ b2,
                             const float* __restrict__ Wfc, const float* __restrict__ bfc,
                             float* __restrict__ out, int G) {
    int g = blockIdx.x * blockDim.x + threadIdx.x;
    if (g >= G) return;
    float cnt = (float)(endg[g] - startg[g]);
    float inv = 1.0f / fmaxf(cnt, 1.0f);
    float s0 = 0.f, s1 = 0.f;
#pragma unroll
    for (int j = 0; j < H; j++) {
        float p = fmaf(pooled[g * H + j], inv, b2[j]);
        s0 = fmaf(p, Wfc[j * 2 + 0], s0);
        s1 = fmaf(p, Wfc[j * 2 + 1], s1);
    }
    out[g * 2 + 0] = s0 + bfc[0];
    out[g * 2 + 1] = s1 + bfc[1];
}

extern "C" void kernel_launch(void* const* d_in, const int* in_sizes, int n_in,
                              void* d_out, int out_size, void* d_ws, size_t ws_size,
                              hipStream_t stream) {
    const float* x    = (const float*)d_in[0];
    const float* W1   = (const float*)d_in[1];
    const float* b1   = (const float*)d_in[2];
    const float* W2   = (const float*)d_in[3];
    const float* b2   = (const float*)d_in[4];
    const float* Wfc  = (const float*)d_in[5];
    const float* bfc  = (const float*)d_in[6];
    const int*   eidx = (const int*)d_in[7];
    const int*   batch= (const int*)d_in[8];
    float* out = (float*)d_out;

    const int N = in_sizes[0] / 5;
    const int E = in_sizes[7] / 2;
    const int G = out_size / 2;

    const int* src = eidx;
    const int* dst = eidx + E;

    char* ws = (char*)d_ws;
    size_t off = 0;
    auto alloc = [&](size_t bytes) { char* p = ws + off; off = (off + bytes + 255) & ~(size_t)255; return p; };
    int*   R      = (int*)alloc((size_t)N * 4);          // counts -> rowptr (in place)
    int*   cursor = (int*)alloc((size_t)N * 4);
    int*   adj    = (int*)alloc((size_t)E * 4);
    int*   bsum   = (int*)alloc(4096);                   // up to 1024 block sums
    float* dinv   = (float*)alloc((size_t)N * 4);
    float* S1     = (float*)alloc((size_t)N * H * 4);
    float* S2     = (float*)alloc((size_t)N * H * 4);
    float* pooled = (float*)alloc((size_t)G * H * 4);
    int*   startg = (int*)alloc((size_t)G * 4);
    int*   endg   = (int*)alloc((size_t)G * 4);
    (void)ws_size;

    const int T = 256;
    auto nb = [&](long long n) { return (int)((n + T - 1) / T); };
    const int nscan = (N + 1023) / 1024;   // 489 for N=500k (must be <= 1024)

    hipMemsetAsync(R, 0, (size_t)N * 4, stream);
    hipMemsetAsync(cursor, 0, (size_t)N * 4, stream);
    hipMemsetAsync(pooled, 0, (size_t)G * H * 4, stream);
    hipMemsetAsync(startg, 0, (size_t)G * 4, stream);
    hipMemsetAsync(endg, 0, (size_t)G * 4, stream);

    // CSR build
    hist_kernel<<<nb(E), T, 0, stream>>>(dst, R, E);
    scan1_kernel<<<nscan, 256, 0, stream>>>(R, bsum, N);
    scan2_kernel<<<1, 1024, 0, stream>>>(bsum, nscan);
    scan3_kernel<<<nb(N), T, 0, stream>>>(R, bsum, N);
    dinv_kernel<<<nb(N), T, 0, stream>>>(R, dinv, N, E);
    scatter_kernel<<<nb(E), T, 0, stream>>>(src, dst, R, cursor, adj, E);

    // layer 1
    lin1_kernel<<<nb(N), T, 0, stream>>>(x, W1, dinv, S1, N);
    pull_kernel<<<nb((long long)N * H), T, 0, stream>>>(S1, R, adj, dinv, b1, S2, N, E, 1);

    // layer 2
    lin2_kernel<<<nb(N), T, 0, stream>>>(W2, dinv, S2, N);
    pull_kernel<<<nb((long long)N * H), T, 0, stream>>>(S2, R, adj, dinv, nullptr, S1, N, E, 0);

    // pool + fc
    bounds_kernel<<<nb(N), T, 0, stream>>>(batch, startg, endg, N);
    pool_kernel<<<(N + POOL_CHUNK - 1) / POOL_CHUNK, T, 0, stream>>>(S1, batch, pooled, N);
    final_kernel<<<nb(G), T, 0, stream>>>(pooled, startg, endg, b2, Wfc, bfc, out, G);
}

// Round 4
// 455.795 us; speedup vs baseline: 2.5807x; 1.4985x over previous
//
#include <hip/hip_runtime.h>

// GCN via CSR pull-aggregation, float4-vectorized (8 lanes per node row).
// s[i] = (h@W)[i]*dinv[i];  conv[i] = dinv[i]*(s[i] + sum_{u in nbr_in(i)} s[u]) + b
// Layer-1 pull fuses the W2 transform in its epilogue via LDS row exchange.

constexpr int H = 32;
constexpr int POOL_CHUNK = 1024;

// ---- CSR build ----
__global__ void hist_kernel(const int* __restrict__ dst, int* __restrict__ cnt, int E) {
    int e = blockIdx.x * blockDim.x + threadIdx.x;
    if (e < E) atomicAdd(&cnt[dst[e]], 1);
}

// scan1: in-place exclusive scan of 1024-element chunks of R; block totals -> bsum.
// Also emits dinv[i] = rsqrt(count_i + 1) while counts are in registers.
__global__ void scan1_kernel(int* __restrict__ R, int* __restrict__ bsum,
                             float* __restrict__ dinv, int N) {
    __shared__ int sh[256];
    int base = blockIdx.x * 1024 + threadIdx.x * 4;
    int v[4]; int s = 0;
#pragma unroll
    for (int q = 0; q < 4; q++) {
        int idx = base + q;
        v[q] = (idx < N) ? R[idx] : 0;
        if (idx < N) dinv[idx] = rsqrtf((float)v[q] + 1.0f);
        s += v[q];
    }
    sh[threadIdx.x] = s;
    __syncthreads();
    for (int off = 1; off < 256; off <<= 1) {
        int t = (threadIdx.x >= off) ? sh[threadIdx.x - off] : 0;
        __syncthreads();
        sh[threadIdx.x] += t;
        __syncthreads();
    }
    int excl = sh[threadIdx.x] - s;
#pragma unroll
    for (int q = 0; q < 4; q++) { int idx = base + q; if (idx < N) R[idx] = excl; excl += v[q]; }
    if (threadIdx.x == 255) bsum[blockIdx.x] = sh[255];
}

__global__ void scan2_kernel(int* __restrict__ bsum, int nb) {
    __shared__ int sh[1024];
    int t = threadIdx.x;
    int orig = (t < nb) ? bsum[t] : 0;
    sh[t] = orig;
    __syncthreads();
    for (int off = 1; off < 1024; off <<= 1) {
        int v = (t >= off) ? sh[t - off] : 0;
        __syncthreads();
        sh[t] += v;
        __syncthreads();
    }
    if (t < nb) bsum[t] = sh[t] - orig;
}

__global__ void scan3_kernel(int* __restrict__ R, const int* __restrict__ bsum, int N) {
    int i = blockIdx.x * blockDim.x + threadIdx.x;
    if (i < N) R[i] += bsum[i >> 10];
}

__global__ void scatter_kernel(const int* __restrict__ src, const int* __restrict__ dst,
                               const int* __restrict__ R, int* __restrict__ cursor,
                               int* __restrict__ adj, int E) {
    int e = blockIdx.x * blockDim.x + threadIdx.x;
    if (e >= E) return;
    int v = dst[e];
    int pos = R[v] + atomicAdd(&cursor[v], 1);
    adj[pos] = src[e];
}

// ---- lin1: S[i][4q..4q+3] = dinv[i] * x[i] @ W1[:,4q..4q+3], coalesced float4 stores
__global__ void lin1_kernel(const float* __restrict__ x, const float4* __restrict__ W1v,
                            const float* __restrict__ dinv, float4* __restrict__ S, int N) {
    int t = blockIdx.x * blockDim.x + threadIdx.x;
    int i = t >> 3, q = t & 7;
    if (i >= N) return;
    float di = dinv[i];
    float4 o = make_float4(0.f, 0.f, 0.f, 0.f);
#pragma unroll
    for (int k = 0; k < 5; k++) {
        float xv = x[i * 5 + k];
        float4 w = W1v[k * 8 + q];            // W1[k][4q..4q+3]
        o.x = fmaf(xv, w.x, o.x); o.y = fmaf(xv, w.y, o.y);
        o.z = fmaf(xv, w.z, o.z); o.w = fmaf(xv, w.w, o.w);
    }
    o.x *= di; o.y *= di; o.z *= di; o.w *= di;
    S[(size_t)i * 8 + q] = o;
}

// ---- pull: val[i][q] = RELU?( dinv*(self + sum_nbr) + bias );
// FUSE_W2: Sout[i] = dinv[i] * (val_row @ W2) via LDS row exchange.
template<int RELU, int FUSE_W2>
__global__ void pull_kernel(const float4* __restrict__ Sin, const int* __restrict__ R,
                            const int* __restrict__ adj, const float* __restrict__ dinv,
                            const float* __restrict__ bias, const float4* __restrict__ W2v,
                            float4* __restrict__ Sout, int N, int E) {
    __shared__ float hsh[32][33];   // 32 node rows, +1 pad
    __shared__ float4 wsh[32][8];   // W2: wsh[k][q] = W2[k][4q..4q+3]
    int t = blockIdx.x * blockDim.x + threadIdx.x;
    int i = t >> 3, q = t & 7;
    if (FUSE_W2) {
        wsh[threadIdx.x >> 3][threadIdx.x & 7] = W2v[threadIdx.x];  // 256 float4 = full W2
    }
    bool active = (i < N);
    float4 val = make_float4(0.f, 0.f, 0.f, 0.f);
    float di = 0.f;
    if (active) {
        float4 acc = Sin[(size_t)i * 8 + q];            // self-loop
        int s = R[i];
        int e2 = (i == N - 1) ? E : R[i + 1];
        for (int k = s; k < e2; k++) {
            int u = adj[k];
            float4 v = Sin[(size_t)u * 8 + q];
            acc.x += v.x; acc.y += v.y; acc.z += v.z; acc.w += v.w;
        }
        di = dinv[i];
        float4 b = bias ? make_float4(bias[q*4], bias[q*4+1], bias[q*4+2], bias[q*4+3])
                        : make_float4(0.f, 0.f, 0.f, 0.f);
        val.x = fmaf(di, acc.x, b.x); val.y = fmaf(di, acc.y, b.y);
        val.z = fmaf(di, acc.z, b.z); val.w = fmaf(di, acc.w, b.w);
        if (RELU) {
            val.x = fmaxf(val.x, 0.f); val.y = fmaxf(val.y, 0.f);
            val.z = fmaxf(val.z, 0.f); val.w = fmaxf(val.w, 0.f);
        }
    }
    if constexpr (FUSE_W2) {
        int local = threadIdx.x >> 3;
        if (active) {
            hsh[local][q * 4 + 0] = val.x; hsh[local][q * 4 + 1] = val.y;
            hsh[local][q * 4 + 2] = val.z; hsh[local][q * 4 + 3] = val.w;
        }
        __syncthreads();
        if (active) {
            float4 o = make_float4(0.f, 0.f, 0.f, 0.f);
#pragma unroll
            for (int k = 0; k < H; k++) {
                float hk = hsh[local][k];
                float4 w = wsh[k][q];
                o.x = fmaf(hk, w.x, o.x); o.y = fmaf(hk, w.y, o.y);
                o.z = fmaf(hk, w.z, o.z); o.w = fmaf(hk, w.w, o.w);
            }
            o.x *= di; o.y *= di; o.z *= di; o.w *= di;
            Sout[(size_t)i * 8 + q] = o;
        }
    } else {
        if (active) Sout[(size_t)i * 8 + q] = val;
    }
}

// ---- pooling ----
__global__ void bounds_kernel(const int* __restrict__ batch, int* __restrict__ startg,
                              int* __restrict__ endg, int N) {
    int i = blockIdx.x * blockDim.x + threadIdx.x;
    if (i >= N) return;
    int g = batch[i];
    if (i == 0 || batch[i - 1] != g) startg[g] = i;
    if (i == N - 1 || batch[i + 1] != g) endg[g] = i + 1;
}

// segmented sum over sorted batch; one atomic flush per (run x thread), float4 reads
__global__ void pool_kernel(const float4* __restrict__ H2, const int* __restrict__ batch,
                            float* __restrict__ pooled, int N) {
    const int q = threadIdx.x & 7;
    const int r = threadIdx.x >> 3;        // 0..31 rows in flight
    const int ROWS = 32;
    long long base = (long long)blockIdx.x * POOL_CHUNK;
    long long end = base + POOL_CHUNK;
    if (end > N) end = N;
    float4 acc = make_float4(0.f, 0.f, 0.f, 0.f);
    int cur_g = -1;
    for (long long i = base + r; i < end; i += ROWS) {
        int g = batch[i];
        float4 v = H2[i * 8 + q];
        if (g != cur_g) {
            if (cur_g >= 0) {
                float* p = &pooled[(size_t)cur_g * H + q * 4];
                atomicAdd(p + 0, acc.x); atomicAdd(p + 1, acc.y);
                atomicAdd(p + 2, acc.z); atomicAdd(p + 3, acc.w);
            }
            acc = make_float4(0.f, 0.f, 0.f, 0.f);
            cur_g = g;
        }
        acc.x += v.x; acc.y += v.y; acc.z += v.z; acc.w += v.w;
    }
    if (cur_g >= 0) {
        float* p = &pooled[(size_t)cur_g * H + q * 4];
        atomicAdd(p + 0, acc.x); atomicAdd(p + 1, acc.y);
        atomicAdd(p + 2, acc.z); atomicAdd(p + 3, acc.w);
    }
}

// out[g] = (pooled[g]/cnt + b2) @ Wfc + bfc   (b2 commutes through mean)
__global__ void final_kernel(const float* __restrict__ pooled, const int* __restrict__ startg,
                             const int* __restrict__ endg, const float* __restrict__ b2,
                             const float* __restrict__ Wfc, const float* __restrict__ bfc,
                             float* __restrict__ out, int G) {
    int g = blockIdx.x * blockDim.x + threadIdx.x;
    if (g >= G) return;
    float cnt = (float)(endg[g] - startg[g]);
    float inv = 1.0f / fmaxf(cnt, 1.0f);
    float s0 = 0.f, s1 = 0.f;
#pragma unroll
    for (int j = 0; j < H; j++) {
        float p = fmaf(pooled[g * H + j], inv, b2[j]);
        s0 = fmaf(p, Wfc[j * 2 + 0], s0);
        s1 = fmaf(p, Wfc[j * 2 + 1], s1);
    }
    out[g * 2 + 0] = s0 + bfc[0];
    out[g * 2 + 1] = s1 + bfc[1];
}

extern "C" void kernel_launch(void* const* d_in, const int* in_sizes, int n_in,
                              void* d_out, int out_size, void* d_ws, size_t ws_size,
                              hipStream_t stream) {
    const float* x    = (const float*)d_in[0];
    const float* W1   = (const float*)d_in[1];
    const float* b1   = (const float*)d_in[2];
    const float* W2   = (const float*)d_in[3];
    const float* b2   = (const float*)d_in[4];
    const float* Wfc  = (const float*)d_in[5];
    const float* bfc  = (const float*)d_in[6];
    const int*   eidx = (const int*)d_in[7];
    const int*   batch= (const int*)d_in[8];
    float* out = (float*)d_out;

    const int N = in_sizes[0] / 5;
    const int E = in_sizes[7] / 2;
    const int G = out_size / 2;

    const int* src = eidx;
    const int* dst = eidx + E;

    char* ws = (char*)d_ws;
    size_t off = 0;
    auto alloc = [&](size_t bytes) { char* p = ws + off; off = (off + bytes + 255) & ~(size_t)255; return p; };
    size_t Npad = ((size_t)N * 4 + 255) & ~(size_t)255;
    int*   R      = (int*)alloc((size_t)N * 4);          // counts -> rowptr (in place)
    int*   cursor = (int*)alloc((size_t)N * 4);          // contiguous with R
    int*   adj    = (int*)alloc((size_t)E * 4);
    int*   bsum   = (int*)alloc(4096);
    float* dinv   = (float*)alloc((size_t)N * 4);
    float* S1     = (float*)alloc((size_t)N * H * 4);
    float* S2     = (float*)alloc((size_t)N * H * 4);
    float* pooled = (float*)alloc((size_t)G * H * 4);    // pooled/startg/endg contiguous
    int*   startg = (int*)alloc((size_t)G * 4);
    int*   endg   = (int*)alloc((size_t)G * 4);
    (void)ws_size;

    const int T = 256;
    auto nb = [&](long long n) { return (int)((n + T - 1) / T); };
    const int nscan = (N + 1023) / 1024;   // 489 for N=500k (must be <= 1024)

    hipMemsetAsync(R, 0, Npad * 2, stream);                                   // R + cursor
    hipMemsetAsync(pooled, 0, (size_t)G * H * 4 + (size_t)G * 4 * 2, stream); // pooled+startg+endg

    // CSR build (dinv fused into scan1)
    hist_kernel<<<nb(E), T, 0, stream>>>(dst, R, E);
    scan1_kernel<<<nscan, 256, 0, stream>>>(R, bsum, dinv, N);
    scan2_kernel<<<1, 1024, 0, stream>>>(bsum, nscan);
    scan3_kernel<<<nb(N), T, 0, stream>>>(R, bsum, N);
    scatter_kernel<<<nb(E), T, 0, stream>>>(src, dst, R, cursor, adj, E);

    // layer 1 (+ fused W2 transform)
    lin1_kernel<<<nb((long long)N * 8), T, 0, stream>>>(x, (const float4*)W1, dinv, (float4*)S1, N);
    pull_kernel<1, 1><<<nb((long long)N * 8), T, 0, stream>>>(
        (const float4*)S1, R, adj, dinv, b1, (const float4*)W2, (float4*)S2, N, E);

    // layer 2
    pull_kernel<0, 0><<<nb((long long)N * 8), T, 0, stream>>>(
        (const float4*)S2, R, adj, dinv, nullptr, nullptr, (float4*)S1, N, E);

    // pool + fc
    bounds_kernel<<<nb(N), T, 0, stream>>>(batch, startg, endg, N);
    pool_kernel<<<(N + POOL_CHUNK - 1) / POOL_CHUNK, T, 0, stream>>>(
        (const float4*)S1, batch, pooled, N);
    final_kernel<<<nb(G), T, 0, stream>>>(pooled, startg, endg, b2, Wfc, bfc, out, G);
}